// Round 3
// baseline (478.064 us; speedup 1.0000x reference)
//
#include <hip/hip_runtime.h>

// GestureRNN v3: K-split (P=2) LDS-transpose RNN. B=4096, T=512, IN=10, H=32.
// Per 32-lane half (one batch element): lane (u,p), u=0..15, p=0..1 owns
// units {u, u+16} restricted to K-chunk [16p, 16p+16) (and x-inputs
// [5p, 5p+5)). Partial dots are combined with one ds_swizzle xor-16 + add
// (v2-verified). h chunks are carried in REGISTERS across steps; LDS is only
// the unit-distribution -> chunk-distribution transpose medium:
// 8 ds_read_b128 + 2 paired writes + 4 swizzles per wave-step (vs v1's 26 DS).
// Single-wave blocks: __syncthreads() compiles to just the lgkmcnt wait.

constexpr int T_  = 512;
constexpr int IN_ = 10;
constexpr int H_  = 32;
constexpr int NC_ = 9;

__device__ __forceinline__ float swz16(float v) {
    // lane <-> lane^16 within each 32-lane half (BitMode xor=16, and=0x1F)
    return __int_as_float(__builtin_amdgcn_ds_swizzle(__float_as_int(v), 0x401F));
}

__global__ __launch_bounds__(64, 2) void gesture_rnn_kernel(
    const float* __restrict__ x,      // [B, T, IN]
    const float* __restrict__ W_ih0,  // [H, IN]
    const float* __restrict__ W_hh0,  // [H, H]
    const float* __restrict__ b_ih0,  // [H]
    const float* __restrict__ b_hh0,  // [H]
    const float* __restrict__ W_ih1,  // [H, H]
    const float* __restrict__ W_hh1,  // [H, H]
    const float* __restrict__ b_ih1,  // [H]
    const float* __restrict__ b_hh1,  // [H]
    const float* __restrict__ W_fc,   // [NC, H]
    const float* __restrict__ b_fc,   // [NC]
    float* __restrict__ out)          // [B, NC]
{
    const int lane = threadIdx.x;     // 0..63
    const int g    = lane >> 5;       // batch half within wave
    const int l    = lane & 31;
    const int p    = l >> 4;          // K-group: chunk [16p, 16p+16)
    const int u    = l & 15;          // owns units u and u+16
    const long b   = (long)blockIdx.x * 2 + g;

    const int uA = u, uB = u + 16, k0 = p * 16;

    // ---- register weight chunks: rows uA,uB restricted to this lane's K ----
    float w0a[16], w0b[16];   // W_hh0
    float w1a[16], w1b[16];   // W_ih1
    float w2a[16], w2b[16];   // W_hh1
#pragma unroll
    for (int k = 0; k < 16; ++k) {
        w0a[k] = W_hh0[uA * H_ + k0 + k];
        w0b[k] = W_hh0[uB * H_ + k0 + k];
        w1a[k] = W_ih1[uA * H_ + k0 + k];
        w1b[k] = W_ih1[uB * H_ + k0 + k];
        w2a[k] = W_hh1[uA * H_ + k0 + k];
        w2b[k] = W_hh1[uB * H_ + k0 + k];
    }
    float wxa[5], wxb[5];     // W_ih0, inputs [5p, 5p+5)
#pragma unroll
    for (int i = 0; i < 5; ++i) {
        wxa[i] = W_ih0[uA * IN_ + 5 * p + i];
        wxb[i] = W_ih0[uB * IN_ + 5 * p + i];
    }
    // biases folded into the p==0 partial only (added exactly once per unit)
    const float biasA0 = (p == 0) ? (b_ih0[uA] + b_hh0[uA]) : 0.f;
    const float biasB0 = (p == 0) ? (b_ih0[uB] + b_hh0[uB]) : 0.f;
    const float biasA1 = (p == 0) ? (b_ih1[uA] + b_hh1[uA]) : 0.f;
    const float biasB1 = (p == 0) ? (b_ih1[uB] + b_hh1[uB]) : 0.f;

    __shared__ __align__(16) float h1s[2][H_];
    __shared__ __align__(16) float h2s[2][H_];

    // register-carried h chunks (this lane's K-window of h1_old / h2_old)
    float ch1[16], ch2[16];
#pragma unroll
    for (int k = 0; k < 16; ++k) { ch1[k] = 0.f; ch2[k] = 0.f; }

    const float* xb = x + (size_t)b * T_ * IN_ + 5 * p;
    float xv[5], xn[5];
#pragma unroll
    for (int i = 0; i < 5; ++i) xv[i] = xb[i];

#pragma unroll 1
    for (int t = 0; t < T_; ++t) {
        // ---- layer-1 recurrent partial (W_hh1 . h2_old chunk) ----
        float rA0 = biasA1, rA1 = 0.f, rB0 = biasB1, rB1 = 0.f;
#pragma unroll
        for (int k = 0; k < 16; k += 2) {
            rA0 = fmaf(w2a[k],     ch2[k],     rA0);
            rA1 = fmaf(w2a[k + 1], ch2[k + 1], rA1);
            rB0 = fmaf(w2b[k],     ch2[k],     rB0);
            rB1 = fmaf(w2b[k + 1], ch2[k + 1], rB1);
        }

        // ---- layer-0 partial: x-chunk + W_hh0 . h1_old chunk ----
        float aA0 = biasA0, aA1 = 0.f, aB0 = biasB0, aB1 = 0.f;
#pragma unroll
        for (int i = 0; i < 5; ++i) {
            aA0 = fmaf(wxa[i], xv[i], aA0);
            aB0 = fmaf(wxb[i], xv[i], aB0);
        }
#pragma unroll
        for (int k = 0; k < 16; k += 2) {
            aA0 = fmaf(w0a[k],     ch1[k],     aA0);
            aA1 = fmaf(w0a[k + 1], ch1[k + 1], aA1);
            aB0 = fmaf(w0b[k],     ch1[k],     aB0);
            aB1 = fmaf(w0b[k + 1], ch1[k + 1], aB1);
        }
        // cross-lane reduce (p0 partial + p1 partial) + ReLU
        float sA = aA0 + aA1; sA += swz16(sA);
        float sB = aB0 + aB1; sB += swz16(sB);
        const float h1A = fmaxf(sA, 0.f);
        const float h1B = fmaxf(sB, 0.f);

        // publish h1_new (unit-distributed -> chunk layout via LDS)
        if (p == 0) { h1s[g][u] = h1A; h1s[g][uB] = h1B; }
        __syncthreads();   // single wave: compiles to lgkmcnt wait only

        // prefetch next step's x while the transpose drains
        if (t + 1 < T_) {
            const float* xq = xb + (size_t)(t + 1) * IN_;
#pragma unroll
            for (int i = 0; i < 5; ++i) xn[i] = xq[i];
        }

        // read h1_new chunk (becomes ch1 for next step)
        float ch1n[16];
        {
            const float4* src = (const float4*)&h1s[g][k0];
            float4 c0 = src[0], c1 = src[1], c2 = src[2], c3 = src[3];
            ch1n[0]=c0.x; ch1n[1]=c0.y; ch1n[2]=c0.z; ch1n[3]=c0.w;
            ch1n[4]=c1.x; ch1n[5]=c1.y; ch1n[6]=c1.z; ch1n[7]=c1.w;
            ch1n[8]=c2.x; ch1n[9]=c2.y; ch1n[10]=c2.z; ch1n[11]=c2.w;
            ch1n[12]=c3.x; ch1n[13]=c3.y; ch1n[14]=c3.z; ch1n[15]=c3.w;
        }

        // ---- layer-1 input partial (W_ih1 . h1_new chunk) ----
#pragma unroll
        for (int k = 0; k < 16; k += 2) {
            rA0 = fmaf(w1a[k],     ch1n[k],     rA0);
            rA1 = fmaf(w1a[k + 1], ch1n[k + 1], rA1);
            rB0 = fmaf(w1b[k],     ch1n[k],     rB0);
            rB1 = fmaf(w1b[k + 1], ch1n[k + 1], rB1);
        }
        float tA = rA0 + rA1; tA += swz16(tA);
        float tB = rB0 + rB1; tB += swz16(tB);
        const float h2A = fmaxf(tA, 0.f);
        const float h2B = fmaxf(tB, 0.f);

        if (p == 0) { h2s[g][u] = h2A; h2s[g][uB] = h2B; }
        __syncthreads();

        // read h2_new chunk now; latency hides into next step's layer-0
        {
            const float4* src = (const float4*)&h2s[g][k0];
            float4 c0 = src[0], c1 = src[1], c2 = src[2], c3 = src[3];
            ch2[0]=c0.x; ch2[1]=c0.y; ch2[2]=c0.z; ch2[3]=c0.w;
            ch2[4]=c1.x; ch2[5]=c1.y; ch2[6]=c1.z; ch2[7]=c1.w;
            ch2[8]=c2.x; ch2[9]=c2.y; ch2[10]=c2.z; ch2[11]=c2.w;
            ch2[12]=c3.x; ch2[13]=c3.y; ch2[14]=c3.z; ch2[15]=c3.w;
        }
#pragma unroll
        for (int k = 0; k < 16; ++k) ch1[k] = ch1n[k];
#pragma unroll
        for (int i = 0; i < 5; ++i) xv[i] = xn[i];
    }

    // ---- epilogue: out[b, c] = W_fc[c,:] . h2_last + b_fc[c] ----
    if (l < NC_) {
        float acc = b_fc[l];
#pragma unroll
        for (int k = 0; k < H_; ++k)
            acc = fmaf(W_fc[l * H_ + k], h2s[g][k], acc);
        out[b * NC_ + l] = acc;
    }
}

extern "C" void kernel_launch(void* const* d_in, const int* in_sizes, int n_in,
                              void* d_out, int out_size, void* d_ws, size_t ws_size,
                              hipStream_t stream) {
    const float* x     = (const float*)d_in[0];
    const float* W_ih0 = (const float*)d_in[1];
    const float* W_hh0 = (const float*)d_in[2];
    const float* b_ih0 = (const float*)d_in[3];
    const float* b_hh0 = (const float*)d_in[4];
    const float* W_ih1 = (const float*)d_in[5];
    const float* W_hh1 = (const float*)d_in[6];
    const float* b_ih1 = (const float*)d_in[7];
    const float* b_hh1 = (const float*)d_in[8];
    const float* W_fc  = (const float*)d_in[9];
    const float* b_fc  = (const float*)d_in[10];
    float* out = (float*)d_out;

    const int B = 4096;
    gesture_rnn_kernel<<<dim3(B / 2), dim3(64), 0, stream>>>(
        x, W_ih0, W_hh0, b_ih0, b_hh0, W_ih1, W_hh1, b_ih1, b_hh1,
        W_fc, b_fc, out);
}

// Round 4
// 362.588 us; speedup vs baseline: 1.3185x; 1.3185x over previous
//
#include <hip/hip_runtime.h>

// GestureRNN v4: layer-pipelined single-wave RNN. B=4096, T=512, IN=10, H=32.
// v1/v3 post-mortem: the kernel is latency-bound on the serial per-step chain.
// v4 exploits the independence of h1[i] and h2[i-1]: iteration i computes BOTH
// from the same published state (h1[i-1], h2[i-2]) -> one LDS read burst,
// 106 independent FMAs, 2 writes, one fence per step (v1 had 3 barriers and
// two sequential matvec+LDS round-trips). Single-wave blocks: DS ops are
// wave-ordered, s_barrier elided; __syncthreads is a compiler fence.

constexpr int T_  = 512;
constexpr int IN_ = 10;
constexpr int H_  = 32;
constexpr int NC_ = 9;

__global__ __launch_bounds__(64, 1) void gesture_rnn_kernel(
    const float* __restrict__ x,      // [B, T, IN]
    const float* __restrict__ W_ih0,  // [H, IN]
    const float* __restrict__ W_hh0,  // [H, H]
    const float* __restrict__ b_ih0,  // [H]
    const float* __restrict__ b_hh0,  // [H]
    const float* __restrict__ W_ih1,  // [H, H]
    const float* __restrict__ W_hh1,  // [H, H]
    const float* __restrict__ b_ih1,  // [H]
    const float* __restrict__ b_hh1,  // [H]
    const float* __restrict__ W_fc,   // [NC, H]
    const float* __restrict__ b_fc,   // [NC]
    float* __restrict__ out)          // [B, NC]
{
    const int lane = threadIdx.x;     // 0..63
    const int g    = lane >> 5;       // batch element within wave
    const int j    = lane & 31;       // hidden unit owned by this lane
    const long b   = (long)blockIdx.x * 2 + g;

    // ---- register-cached weight rows for hidden unit j ----
    float wx[IN_];
    float whh0[H_], wih1[H_], whh1[H_];
#pragma unroll
    for (int i = 0; i < IN_; ++i) wx[i] = W_ih0[j * IN_ + i];
#pragma unroll
    for (int k = 0; k < H_; ++k) {
        whh0[k] = W_hh0[j * H_ + k];
        wih1[k] = W_ih1[j * H_ + k];
        whh1[k] = W_hh1[j * H_ + k];
    }
    const float bias0 = b_ih0[j] + b_hh0[j];
    const float bias1 = b_ih1[j] + b_hh1[j];

    // state: hs[g][0..31] = h1, hs[g][32..63] = h2
    __shared__ __align__(16) float hs[2][2 * H_];

    const float* xp = x + (size_t)b * T_ * IN_;
    float xv[IN_];
#pragma unroll
    for (int i = 0; i < IN_; i += 2) {
        float2 v = *(const float2*)(xp + i);
        xv[i] = v.x; xv[i + 1] = v.y;
    }

    // ---- prologue: h1[0] = relu(xproj(x[0])), h2[-1] = 0 ----
    {
        float a = bias0;
#pragma unroll
        for (int i = 0; i < IN_; ++i) a = fmaf(wx[i], xv[i], a);
        hs[g][j]      = fmaxf(a, 0.f);
        hs[g][H_ + j] = 0.f;
    }
    __syncthreads();

    // preload x[1]
    xp += IN_;
#pragma unroll
    for (int i = 0; i < IN_; i += 2) {
        float2 v = *(const float2*)(xp + i);
        xv[i] = v.x; xv[i + 1] = v.y;
    }

    // ---- main loop: iteration i computes h1[i] and h2[i-1] ----
#pragma unroll 1
    for (int i = 1; i < T_; ++i) {
        // one read burst: h1[i-1] (32 floats) + h2[i-2] (32 floats)
        const float4* src = (const float4*)&hs[g][0];
        const float4 p0 = src[0], p1 = src[1], p2 = src[2], p3 = src[3]; // h1
        const float4 q0 = src[4], q1 = src[5], q2 = src[6], q3 = src[7]; // h2
        const float h1f[16] = {p0.x,p0.y,p0.z,p0.w, p1.x,p1.y,p1.z,p1.w,
                               p2.x,p2.y,p2.z,p2.w, p3.x,p3.y,p3.z,p3.w};
        const float h1g[16] = {q0.x,q0.y,q0.z,q0.w, q1.x,q1.y,q1.z,q1.w,
                               q2.x,q2.y,q2.z,q2.w, q3.x,q3.y,q3.z,q3.w};
        // NOTE: hs[g][0..31]=h1 spans p0..p3 AND q0..q3? No: 32 floats = 8
        // float4 -> h1 = src[0..7], h2 = src[8..15].
        (void)h1f; (void)h1g;
        const float4 p4 = src[4], p5 = src[5], p6 = src[6], p7 = src[7];
        const float4 r0 = src[8],  r1 = src[9],  r2 = src[10], r3 = src[11];
        const float4 r4 = src[12], r5 = src[13], r6 = src[14], r7 = src[15];

        const float h1v[32] = {p0.x,p0.y,p0.z,p0.w, p1.x,p1.y,p1.z,p1.w,
                               p2.x,p2.y,p2.z,p2.w, p3.x,p3.y,p3.z,p3.w,
                               p4.x,p4.y,p4.z,p4.w, p5.x,p5.y,p5.z,p5.w,
                               p6.x,p6.y,p6.z,p6.w, p7.x,p7.y,p7.z,p7.w};
        const float h2v[32] = {r0.x,r0.y,r0.z,r0.w, r1.x,r1.y,r1.z,r1.w,
                               r2.x,r2.y,r2.z,r2.w, r3.x,r3.y,r3.z,r3.w,
                               r4.x,r4.y,r4.z,r4.w, r5.x,r5.y,r5.z,r5.w,
                               r6.x,r6.y,r6.z,r6.w, r7.x,r7.y,r7.z,r7.w};

        // layer-0: a1 = bias0 + wx.x[i] + whh0.h1[i-1]
        float a1A = bias0, a1B = 0.f;
#pragma unroll
        for (int i2 = 0; i2 < IN_; i2 += 2) {
            a1A = fmaf(wx[i2],     xv[i2],     a1A);
            a1B = fmaf(wx[i2 + 1], xv[i2 + 1], a1B);
        }
        // layer-1: a2 = bias1 + wih1.h1[i-1] + whh1.h2[i-2]   (independent)
        float a2A = bias1, a2B = 0.f, a2C = 0.f, a2D = 0.f;
#pragma unroll
        for (int k = 0; k < 16; ++k) {
            a1A = fmaf(whh0[k],      h1v[k],      a1A);
            a1B = fmaf(whh0[k + 16], h1v[k + 16], a1B);
            a2A = fmaf(wih1[k],      h1v[k],      a2A);
            a2B = fmaf(wih1[k + 16], h1v[k + 16], a2B);
            a2C = fmaf(whh1[k],      h2v[k],      a2C);
            a2D = fmaf(whh1[k + 16], h2v[k + 16], a2D);
        }

        // prefetch next x while dots finish
        if (i + 1 < T_) {
            xp += IN_;
#pragma unroll
            for (int i2 = 0; i2 < IN_; i2 += 2) {
                float2 v = *(const float2*)(xp + i2);
                xv[i2] = v.x; xv[i2 + 1] = v.y;
            }
        }

        const float nh1 = fmaxf(a1A + a1B, 0.f);                  // h1[i]
        const float nh2 = fmaxf((a2A + a2B) + (a2C + a2D), 0.f);  // h2[i-1]

        hs[g][j]      = nh1;   // wave-ordered after the reads above
        hs[g][H_ + j] = nh2;
        __syncthreads();
    }

    // ---- epilogue: h2[511] = relu(bias1 + wih1.h1[511] + whh1.h2[510]) ----
    {
        float aA = bias1, aB = 0.f, aC = 0.f, aD = 0.f;
#pragma unroll
        for (int k = 0; k < 16; ++k) {
            aA = fmaf(wih1[k],      hs[g][k],            aA);
            aB = fmaf(wih1[k + 16], hs[g][k + 16],       aB);
            aC = fmaf(whh1[k],      hs[g][H_ + k],       aC);
            aD = fmaf(whh1[k + 16], hs[g][H_ + k + 16],  aD);
        }
        const float nh2 = fmaxf((aA + aB) + (aC + aD), 0.f);
        __syncthreads();
        hs[g][H_ + j] = nh2;
    }
    __syncthreads();

    // ---- FC head: out[b, c] = W_fc[c,:] . h2[511] + b_fc[c] ----
    if (j < NC_) {
        float acc = b_fc[j];
#pragma unroll
        for (int k = 0; k < H_; ++k)
            acc = fmaf(W_fc[j * H_ + k], hs[g][H_ + k], acc);
        out[b * NC_ + j] = acc;
    }
}

extern "C" void kernel_launch(void* const* d_in, const int* in_sizes, int n_in,
                              void* d_out, int out_size, void* d_ws, size_t ws_size,
                              hipStream_t stream) {
    const float* x     = (const float*)d_in[0];
    const float* W_ih0 = (const float*)d_in[1];
    const float* W_hh0 = (const float*)d_in[2];
    const float* b_ih0 = (const float*)d_in[3];
    const float* b_hh0 = (const float*)d_in[4];
    const float* W_ih1 = (const float*)d_in[5];
    const float* W_hh1 = (const float*)d_in[6];
    const float* b_ih1 = (const float*)d_in[7];
    const float* b_hh1 = (const float*)d_in[8];
    const float* W_fc  = (const float*)d_in[9];
    const float* b_fc  = (const float*)d_in[10];
    float* out = (float*)d_out;

    const int B = 4096;
    gesture_rnn_kernel<<<dim3(B / 2), dim3(64), 0, stream>>>(
        x, W_ih0, W_hh0, b_ih0, b_hh0, W_ih1, W_hh1, b_ih1, b_hh1,
        W_fc, b_fc, out);
}

// Round 5
// 333.744 us; speedup vs baseline: 1.4324x; 1.0864x over previous
//
#include <hip/hip_runtime.h>

// GestureRNN v5: f16-state + v_dot2_f32_f16. B=4096, T=512, IN=10, H=32.
// v1/v4 post-mortem: DS-pipe-throughput-bound (~8 cyc/DS-instr, broadcast or
// not). v5 halves state bytes (f16) -> 8 ds_read_b128 + 2 ds_write_b16 per
// wave-step (was 16+2 fp32), and halves MAC instruction count via
// v_dot2_f32_f16 (fp32 accumulate). Weights pre-packed to half2 in VGPRs.
// x-projection stays fp32 for accuracy. Layer-pipelined as v4: iteration i
// computes h1[i] and h2[i-1] from the same published state -> 1 fence/step.
// Single-wave blocks: DS ops wave-ordered, s_barrier elided.

constexpr int T_  = 512;
constexpr int IN_ = 10;
constexpr int H_  = 32;
constexpr int NC_ = 9;

typedef _Float16 h2v __attribute__((ext_vector_type(2)));

union U4H { uint4 u; h2v h[4]; };

__global__ __launch_bounds__(64, 1) void gesture_rnn_kernel(
    const float* __restrict__ x,      // [B, T, IN]
    const float* __restrict__ W_ih0,  // [H, IN]
    const float* __restrict__ W_hh0,  // [H, H]
    const float* __restrict__ b_ih0,  // [H]
    const float* __restrict__ b_hh0,  // [H]
    const float* __restrict__ W_ih1,  // [H, H]
    const float* __restrict__ W_hh1,  // [H, H]
    const float* __restrict__ b_ih1,  // [H]
    const float* __restrict__ b_hh1,  // [H]
    const float* __restrict__ W_fc,   // [NC, H]
    const float* __restrict__ b_fc,   // [NC]
    float* __restrict__ out)          // [B, NC]
{
    const int lane = threadIdx.x;     // 0..63
    const int g    = lane >> 5;       // batch element within wave
    const int j    = lane & 31;       // hidden unit owned by this lane
    const long b   = (long)blockIdx.x * 2 + g;

    // ---- fp32 x-projection weights ----
    float wx[IN_];
#pragma unroll
    for (int i = 0; i < IN_; ++i) wx[i] = W_ih0[j * IN_ + i];

    // ---- half2-packed recurrent weight rows for unit j ----
    h2v w0[16], w1[16], w2[16];
#pragma unroll
    for (int k = 0; k < 16; ++k) {
        w0[k][0] = (_Float16)W_hh0[j * H_ + 2 * k];
        w0[k][1] = (_Float16)W_hh0[j * H_ + 2 * k + 1];
        w1[k][0] = (_Float16)W_ih1[j * H_ + 2 * k];
        w1[k][1] = (_Float16)W_ih1[j * H_ + 2 * k + 1];
        w2[k][0] = (_Float16)W_hh1[j * H_ + 2 * k];
        w2[k][1] = (_Float16)W_hh1[j * H_ + 2 * k + 1];
    }
    const float bias0 = b_ih0[j] + b_hh0[j];
    const float bias1 = b_ih1[j] + b_hh1[j];

    // state (f16): hs[g][0..31] = h1, hs[g][32..63] = h2
    __shared__ __align__(16) _Float16 hs[2][2 * H_];

    const float* xp = x + (size_t)b * T_ * IN_;
    float xv[IN_];
#pragma unroll
    for (int i = 0; i < IN_; i += 2) {
        float2 v = *(const float2*)(xp + i);
        xv[i] = v.x; xv[i + 1] = v.y;
    }

    // ---- prologue: h1[0] = relu(xproj(x[0])), h2[-1] = 0 ----
    {
        float a = bias0;
#pragma unroll
        for (int i = 0; i < IN_; ++i) a = fmaf(wx[i], xv[i], a);
        hs[g][j]      = (_Float16)fmaxf(a, 0.f);
        hs[g][H_ + j] = (_Float16)0.f;
    }
    __syncthreads();

    // preload x[1]
    xp += IN_;
#pragma unroll
    for (int i = 0; i < IN_; i += 2) {
        float2 v = *(const float2*)(xp + i);
        xv[i] = v.x; xv[i + 1] = v.y;
    }

    // ---- main loop: iteration i computes h1[i] and h2[i-1] ----
#pragma unroll 1
    for (int i = 1; i < T_; ++i) {
        // one read burst: 8x ds_read_b128 (h1: 4, h2: 4), operands arrive
        // pre-packed as half2
        h2v h1h[16], h2h[16];
        {
            const uint4* sp = (const uint4*)&hs[g][0];
#pragma unroll
            for (int q = 0; q < 4; ++q) {
                U4H a; a.u = sp[q];
                U4H c; c.u = sp[q + 4];
#pragma unroll
                for (int r = 0; r < 4; ++r) {
                    h1h[4 * q + r] = a.h[r];
                    h2h[4 * q + r] = c.h[r];
                }
            }
        }

        // layer-0 x-projection (fp32)
        float a1A = bias0, a1B = 0.f;
#pragma unroll
        for (int i2 = 0; i2 < IN_; i2 += 2) {
            a1A = fmaf(wx[i2],     xv[i2],     a1A);
            a1B = fmaf(wx[i2 + 1], xv[i2 + 1], a1B);
        }

        // three dots via v_dot2_f32_f16, fp32 accumulators, all independent
        float a2A = bias1, a2B = 0.f, a2C = 0.f, a2D = 0.f;
#pragma unroll
        for (int k = 0; k < 8; ++k) {
            a1A = __builtin_amdgcn_fdot2(w0[k],     h1h[k],     a1A, false);
            a1B = __builtin_amdgcn_fdot2(w0[k + 8], h1h[k + 8], a1B, false);
            a2A = __builtin_amdgcn_fdot2(w1[k],     h1h[k],     a2A, false);
            a2B = __builtin_amdgcn_fdot2(w1[k + 8], h1h[k + 8], a2B, false);
            a2C = __builtin_amdgcn_fdot2(w2[k],     h2h[k],     a2C, false);
            a2D = __builtin_amdgcn_fdot2(w2[k + 8], h2h[k + 8], a2D, false);
        }

        // prefetch next x while dots finish
        if (i + 1 < T_) {
            xp += IN_;
#pragma unroll
            for (int i2 = 0; i2 < IN_; i2 += 2) {
                float2 v = *(const float2*)(xp + i2);
                xv[i2] = v.x; xv[i2 + 1] = v.y;
            }
        }

        const float nh1 = fmaxf(a1A + a1B, 0.f);                  // h1[i]
        const float nh2 = fmaxf((a2A + a2B) + (a2C + a2D), 0.f);  // h2[i-1]

        hs[g][j]      = (_Float16)nh1;   // 2x ds_write_b16, wave-ordered
        hs[g][H_ + j] = (_Float16)nh2;
        __syncthreads();
    }

    // ---- epilogue: h2[511] = relu(bias1 + wih1.h1[511] + whh1.h2[510]) ----
    // runs once; use fp32 weights from global (L2-hot) for the final step
    {
        float aA = bias1, aB = 0.f, aC = 0.f, aD = 0.f;
#pragma unroll
        for (int k = 0; k < 16; ++k) {
            aA = fmaf(W_ih1[j * H_ + k],      (float)hs[g][k],           aA);
            aB = fmaf(W_ih1[j * H_ + k + 16], (float)hs[g][k + 16],      aB);
            aC = fmaf(W_hh1[j * H_ + k],      (float)hs[g][H_ + k],      aC);
            aD = fmaf(W_hh1[j * H_ + k + 16], (float)hs[g][H_ + k + 16], aD);
        }
        const float nh2 = fmaxf((aA + aB) + (aC + aD), 0.f);
        __syncthreads();
        hs[g][H_ + j] = (_Float16)nh2;
    }
    __syncthreads();

    // ---- FC head: out[b, c] = W_fc[c,:] . h2[511] + b_fc[c] ----
    if (j < NC_) {
        float acc = b_fc[j];
#pragma unroll
        for (int k = 0; k < H_; ++k)
            acc = fmaf(W_fc[j * H_ + k], (float)hs[g][H_ + k], acc);
        out[b * NC_ + j] = acc;
    }
}

extern "C" void kernel_launch(void* const* d_in, const int* in_sizes, int n_in,
                              void* d_out, int out_size, void* d_ws, size_t ws_size,
                              hipStream_t stream) {
    const float* x     = (const float*)d_in[0];
    const float* W_ih0 = (const float*)d_in[1];
    const float* W_hh0 = (const float*)d_in[2];
    const float* b_ih0 = (const float*)d_in[3];
    const float* b_hh0 = (const float*)d_in[4];
    const float* W_ih1 = (const float*)d_in[5];
    const float* W_hh1 = (const float*)d_in[6];
    const float* b_ih1 = (const float*)d_in[7];
    const float* b_hh1 = (const float*)d_in[8];
    const float* W_fc  = (const float*)d_in[9];
    const float* b_fc  = (const float*)d_in[10];
    float* out = (float*)d_out;

    const int B = 4096;
    gesture_rnn_kernel<<<dim3(B / 2), dim3(64), 0, stream>>>(
        x, W_ih0, W_hh0, b_ih0, b_hh0, W_ih1, W_hh1, b_ih1, b_hh1,
        W_fc, b_fc, out);
}